// Round 2
// baseline (476.756 us; speedup 1.0000x reference)
//
#include <hip/hip_runtime.h>
#include <hip/hip_bf16.h>
#include <cstdio>

typedef __bf16 bf16_t;
typedef __bf16 bf16x8 __attribute__((ext_vector_type(8)));
typedef __bf16 bf16x4 __attribute__((ext_vector_type(4)));
typedef float  f32x4  __attribute__((ext_vector_type(4)));

#define TM 128
#define TN 128
#define BK 32

// f32 -> bf16 convert, 4 elems/thread, grid-stride
__global__ __launch_bounds__(256)
void cvt_f32_bf16(const float* __restrict__ in, bf16_t* __restrict__ out, int n)
{
    for (int i = (blockIdx.x * 256 + threadIdx.x) * 4; i < n; i += gridDim.x * 256 * 4) {
        const float4 v = *(const float4*)(in + i);
        bf16x4 o;
        o[0] = (bf16_t)v.x; o[1] = (bf16_t)v.y; o[2] = (bf16_t)v.z; o[3] = (bf16_t)v.w;
        *(bf16x4*)(out + i) = o;
    }
}

// Generic NT GEMM: C[m,n] = sum_k A[m,k] * Bm[n,k]   (both row-major, K contiguous)
// MODE 0: += bias(f32), bf16 row-major write (key)
// MODE 1: += bias(f32), bf16 transposed write C + col*Mrows + row (valueT)
// MODE 2: *= scale, bf16 row-major write (scores)
// MODE 3: plain f32 row-major write (final output)
template <int MODE>
__global__ __launch_bounds__(256)
void gemm_nt(const bf16_t* __restrict__ A, const bf16_t* __restrict__ Bm,
             void* __restrict__ Cv, const float* __restrict__ bias,
             float scale, int Mrows, int Ncols, int K,
             long long strideA, long long strideB, long long strideC,
             int tiles_m, int tiles_n)
{
    __shared__ bf16_t As[TM * BK];
    __shared__ bf16_t Bs[TN * BK];

    const int t    = threadIdx.x;
    const int w    = t >> 6;
    const int lane = t & 63;

    const int per_batch = tiles_m * tiles_n;
    const int batch = blockIdx.x / per_batch;
    const int rest  = blockIdx.x % per_batch;
    const int tm    = rest % tiles_m;
    const int tn    = rest / tiles_m;

    const bf16_t* Ab = A + (size_t)batch * strideA + (size_t)tm * TM * K;
    const bf16_t* Bb = Bm + (size_t)batch * strideB + (size_t)tn * TN * K;

    const int wm = w >> 1;      // wave row (0..1) of 64
    const int wn = w & 1;       // wave col (0..1) of 64
    const int lr = lane & 15;   // row (A) / col (B,C) within 16
    const int kq = lane >> 4;   // k-chunk quad (0..3)

    f32x4 acc[4][4];
#pragma unroll
    for (int i = 0; i < 4; i++)
#pragma unroll
        for (int j = 0; j < 4; j++) {
            f32x4 z = {0.f, 0.f, 0.f, 0.f};
            acc[i][j] = z;
        }

    const int arow = t >> 2;        // 0..63: row within a 64-row half
    const int acol = (t & 3) * 8;   // 0,8,16,24: k offset (8 bf16 = 16B)

    for (int k0 = 0; k0 < K; k0 += BK) {
#pragma unroll
        for (int r = 0; r < 2; r++) {
            const bf16_t* ga = Ab + (size_t)(r * 64 + arow) * K + k0 + acol;
            __builtin_amdgcn_global_load_lds(
                (const __attribute__((address_space(1))) void*)ga,
                (__attribute__((address_space(3))) void*)(&As[(r * 256 + w * 64) * 8]),
                16, 0, 0);
            const bf16_t* gb = Bb + (size_t)(r * 64 + arow) * K + k0 + acol;
            __builtin_amdgcn_global_load_lds(
                (const __attribute__((address_space(1))) void*)gb,
                (__attribute__((address_space(3))) void*)(&Bs[(r * 256 + w * 64) * 8]),
                16, 0, 0);
        }
        __syncthreads();

        bf16x8 afrag[4], bfrag[4];
#pragma unroll
        for (int mi = 0; mi < 4; mi++)
            afrag[mi] = *(const bf16x8*)&As[(wm * 64 + mi * 16 + lr) * BK + kq * 8];
#pragma unroll
        for (int ni = 0; ni < 4; ni++)
            bfrag[ni] = *(const bf16x8*)&Bs[(wn * 64 + ni * 16 + lr) * BK + kq * 8];

#pragma unroll
        for (int mi = 0; mi < 4; mi++)
#pragma unroll
            for (int ni = 0; ni < 4; ni++)
                acc[mi][ni] = __builtin_amdgcn_mfma_f32_16x16x32_bf16(
                    afrag[mi], bfrag[ni], acc[mi][ni], 0, 0, 0);
        __syncthreads();
    }

    // Epilogue. C/D layout: col = lane&15, row = (lane>>4)*4 + reg
#pragma unroll
    for (int mi = 0; mi < 4; mi++) {
        const int row_l = wm * 64 + mi * 16 + kq * 4;   // local row base (+reg 0..3)
#pragma unroll
        for (int ni = 0; ni < 4; ni++) {
            const int col = tn * TN + wn * 64 + ni * 16 + lr;   // global col
            f32x4 v = acc[mi][ni];
            if (MODE == 0 || MODE == 1) {
                const float bv = bias[col];
                v[0] += bv; v[1] += bv; v[2] += bv; v[3] += bv;
            }
            if (MODE == 2) {
                v[0] *= scale; v[1] *= scale; v[2] *= scale; v[3] *= scale;
            }
            if (MODE == 1) {
                // transposed store: 4 regs are row-contiguous -> 8B packed store
                bf16_t* p = (bf16_t*)Cv + (size_t)batch * strideC + (size_t)col * Mrows
                              + (size_t)tm * TM + row_l;
                bf16x4 pk;
                pk[0] = (bf16_t)v[0]; pk[1] = (bf16_t)v[1];
                pk[2] = (bf16_t)v[2]; pk[3] = (bf16_t)v[3];
                *(bf16x4*)p = pk;
            } else if (MODE == 3) {
                float* p = (float*)Cv + (size_t)batch * strideC
                              + (size_t)(tm * TM + row_l) * Ncols + col;
                p[0]                 = v[0];
                p[(size_t)Ncols]     = v[1];
                p[2 * (size_t)Ncols] = v[2];
                p[3 * (size_t)Ncols] = v[3];
            } else {
                bf16_t* p = (bf16_t*)Cv + (size_t)batch * strideC
                              + (size_t)(tm * TM + row_l) * Ncols + col;
                p[0]                  = (bf16_t)v[0];
                p[(size_t)Ncols]      = (bf16_t)v[1];
                p[2 * (size_t)Ncols]  = (bf16_t)v[2];
                p[3 * (size_t)Ncols]  = (bf16_t)v[3];
            }
        }
    }
}

// In-place row softmax over rows of length 2048 (bf16), one block per row.
__global__ __launch_bounds__(256)
void softmax_rows(bf16_t* __restrict__ S)
{
    __shared__ float red[8];
    const int t = threadIdx.x;
    const int w = t >> 6;
    const int lane = t & 63;
    bf16_t* p = S + (size_t)blockIdx.x * 2048;

    bf16x8 v = *(const bf16x8*)&p[t * 8];
    float x[8];
    float m = -1e30f;
#pragma unroll
    for (int i = 0; i < 8; i++) { x[i] = (float)v[i]; m = fmaxf(m, x[i]); }
#pragma unroll
    for (int off = 32; off >= 1; off >>= 1) m = fmaxf(m, __shfl_xor(m, off));
    if (lane == 0) red[w] = m;
    __syncthreads();
    m = fmaxf(fmaxf(red[0], red[1]), fmaxf(red[2], red[3]));

    float s = 0.f;
#pragma unroll
    for (int i = 0; i < 8; i++) { x[i] = __expf(x[i] - m); s += x[i]; }
#pragma unroll
    for (int off = 32; off >= 1; off >>= 1) s += __shfl_xor(s, off);
    if (lane == 0) red[4 + w] = s;
    __syncthreads();
    const float inv = 1.f / (red[4] + red[5] + red[6] + red[7]);

    bf16x8 o;
#pragma unroll
    for (int i = 0; i < 8; i++) o[i] = (bf16_t)(x[i] * inv);
    *(bf16x8*)&p[t * 8] = o;
}

extern "C" void kernel_launch(void* const* d_in, const int* in_sizes, int n_in,
                              void* d_out, int out_size, void* d_ws, size_t ws_size,
                              hipStream_t stream)
{
    const int Bn = 8, Nn = 2048, Dd = 1024;   // D_OUT == Dd

    const float* x  = (const float*)d_in[0];
    const float* Wa = (const float*)d_in[1];
    const float* ba = (const float*)d_in[2];
    const float* Wo = (const float*)d_in[3];
    const float* bo = (const float*)d_in[4];
    float* out = (float*)d_out;

    const size_t nX = (size_t)Bn * Nn * Dd;   // 16,777,216
    const size_t nW = (size_t)Dd * Dd;        // 1,048,576
    const size_t nS = (size_t)Bn * Nn * Nn;   // 33,554,432

    bf16_t* xb  = (bf16_t*)d_ws;          // [B, N, D] bf16
    bf16_t* Wab = xb + nX;                // [D, D]
    bf16_t* Wob = Wab + nW;               // [D, D]
    bf16_t* key = Wob + nW;               // [B, N, D]
    bf16_t* vT  = key + nX;               // [B, D, N]
    bf16_t* S   = vT + nX;                // [B, N, N]
    const size_t needed = (nX * 3 + nW * 2 + nS) * sizeof(bf16_t);
    if (ws_size < needed)
        fprintf(stderr, "kernel_launch: ws too small: have %zu need %zu\n", ws_size, needed);

    const dim3 blk(256);
    const long long sXN = (long long)Nn * Dd;   // x / key batch stride
    const long long sS  = (long long)Nn * Nn;   // scores batch stride
    const long long sVT = (long long)Dd * Nn;   // valueT batch stride

    // convert f32 inputs to bf16
    cvt_f32_bf16<<<dim3(16384), blk, 0, stream>>>(x, xb, (int)nX);
    cvt_f32_bf16<<<dim3(1024), blk, 0, stream>>>(Wa, Wab, (int)nW);
    cvt_f32_bf16<<<dim3(1024), blk, 0, stream>>>(Wo, Wob, (int)nW);

    // key = x @ W_attn^T + b_attn     [B,N,D] bf16
    gemm_nt<0><<<dim3(Bn * 16 * 8), blk, 0, stream>>>(
        xb, Wab, key, ba, 1.0f, Nn, Dd, Dd, sXN, 0LL, sXN, 16, 8);

    // valueT = (x @ W_out^T + b_out)^T   [B,D,N] bf16
    gemm_nt<1><<<dim3(Bn * 16 * 8), blk, 0, stream>>>(
        xb, Wob, vT, bo, 1.0f, Nn, Dd, Dd, sXN, 0LL, sVT, 16, 8);

    // S = (x @ key^T) / 32   [B,N,N] bf16
    gemm_nt<2><<<dim3(Bn * 16 * 16), blk, 0, stream>>>(
        xb, key, S, nullptr, 0.03125f, Nn, Nn, Dd, sXN, sXN, sS, 16, 16);

    // P = softmax(S) in place
    softmax_rows<<<dim3(Bn * Nn), blk, 0, stream>>>(S);

    // out = P @ value = P @ (valueT)^T   [B,N,D] f32
    gemm_nt<3><<<dim3(Bn * 16 * 8), blk, 0, stream>>>(
        S, vT, (void*)out, nullptr, 1.0f, Nn, Dd, Nn, sS, sVT, sXN, 16, 8);
}

// Round 3
// 427.401 us; speedup vs baseline: 1.1155x; 1.1155x over previous
//
#include <hip/hip_runtime.h>
#include <hip/hip_bf16.h>
#include <cstdio>

typedef __bf16 bf16_t;
typedef __bf16 bf16x8 __attribute__((ext_vector_type(8)));
typedef __bf16 bf16x4 __attribute__((ext_vector_type(4)));
typedef float  f32x16 __attribute__((ext_vector_type(16)));

#define TM 128
#define TN 128
#define BK 32

// f32 -> bf16 convert, 4 elems/thread, grid-stride
__global__ __launch_bounds__(256)
void cvt_f32_bf16(const float* __restrict__ in, bf16_t* __restrict__ out, int n)
{
    for (int i = (blockIdx.x * 256 + threadIdx.x) * 4; i < n; i += gridDim.x * 256 * 4) {
        const float4 v = *(const float4*)(in + i);
        bf16x4 o;
        o[0] = (bf16_t)v.x; o[1] = (bf16_t)v.y; o[2] = (bf16_t)v.z; o[3] = (bf16_t)v.w;
        *(bf16x4*)(out + i) = o;
    }
}

// ---- shared mainloop pieces -------------------------------------------------
// LDS layout: rows of 32 bf16 (64 B = 4 chunks of 16 B). Chunk c of row r is
// stored at slot c ^ ((r>>1)&3) (XOR swizzle -> conflict-free b128 reads).
// Staging: global SOURCE address is swizzled; LDS dest stays lane-contiguous
// (global_load_lds requires wave-uniform base + lane*16).

__device__ __forceinline__ void stage_tiles(
    const bf16_t* __restrict__ Ab, const bf16_t* __restrict__ Bb,
    bf16_t* As, bf16_t* Bs, int k0, int K, int t, int w)
{
    const int src_c = (t & 3) ^ ((t >> 3) & 3);       // swizzled source chunk
#pragma unroll
    for (int rd = 0; rd < 2; rd++) {
        const int row = rd * 64 + (t >> 2);
        const bf16_t* ga = Ab + (size_t)row * K + k0 + src_c * 8;
        __builtin_amdgcn_global_load_lds(
            (const __attribute__((address_space(1))) void*)ga,
            (__attribute__((address_space(3))) void*)(&As[(rd * 64 + w * 16) * 32]),
            16, 0, 0);
        const bf16_t* gb = Bb + (size_t)row * K + k0 + src_c * 8;
        __builtin_amdgcn_global_load_lds(
            (const __attribute__((address_space(1))) void*)gb,
            (__attribute__((address_space(3))) void*)(&Bs[(rd * 64 + w * 16) * 32]),
            16, 0, 0);
    }
}

// fragment read: row within 128, chunk c in [0,4) -> LDS element index
__device__ __forceinline__ int frag_idx(int row, int c)
{
    return row * 32 + ((c ^ ((row >> 1) & 3)) * 8);
}

// ---- generic NT GEMM (MODE 2: *=scale, bf16 write; MODE 3: f32 write) ------
template <int MODE>
__global__ __launch_bounds__(256)
void gemm_nt(const bf16_t* __restrict__ A, const bf16_t* __restrict__ Bm,
             void* __restrict__ Cv, float scale, int Ncols, int K,
             long long strideA, long long strideB, long long strideC,
             int tiles_m, int tiles_n)
{
    __shared__ bf16_t As[TM * BK];
    __shared__ bf16_t Bs[TN * BK];

    const int t    = threadIdx.x;
    const int w    = t >> 6;
    const int lane = t & 63;
    const int wm = w >> 1, wn = w & 1;
    const int lm = lane & 31;      // row (A) / col (B,C) within 32
    const int lk = lane >> 5;      // k half (0..1)

    const int per_batch = tiles_m * tiles_n;
    const int batch = blockIdx.x / per_batch;
    const int rest  = blockIdx.x % per_batch;
    const int tm    = rest % tiles_m;
    const int tn    = rest / tiles_m;

    const bf16_t* Ab = A + (size_t)batch * strideA + (size_t)tm * TM * K;
    const bf16_t* Bb = Bm + (size_t)batch * strideB + (size_t)tn * TN * K;

    f32x16 acc[2][2];
#pragma unroll
    for (int i = 0; i < 2; i++)
#pragma unroll
        for (int j = 0; j < 2; j++)
#pragma unroll
            for (int e = 0; e < 16; e++) acc[i][j][e] = 0.f;

    for (int k0 = 0; k0 < K; k0 += BK) {
        stage_tiles(Ab, Bb, As, Bs, k0, K, t, w);
        __syncthreads();

        bf16x8 af[2][2], bf[2][2];
#pragma unroll
        for (int ks = 0; ks < 2; ks++) {
#pragma unroll
            for (int mt = 0; mt < 2; mt++)
                af[ks][mt] = *(const bf16x8*)&As[frag_idx(wm * 64 + mt * 32 + lm, ks * 2 + lk)];
#pragma unroll
            for (int nt = 0; nt < 2; nt++)
                bf[ks][nt] = *(const bf16x8*)&Bs[frag_idx(wn * 64 + nt * 32 + lm, ks * 2 + lk)];
        }
#pragma unroll
        for (int ks = 0; ks < 2; ks++)
#pragma unroll
            for (int mt = 0; mt < 2; mt++)
#pragma unroll
                for (int nt = 0; nt < 2; nt++)
                    acc[mt][nt] = __builtin_amdgcn_mfma_f32_32x32x16_bf16(
                        af[ks][mt], bf[ks][nt], acc[mt][nt], 0, 0, 0);
        __syncthreads();
    }

    // Epilogue. 32x32 C/D: col = lane&31, row = (reg&3) + 8*(reg>>2) + 4*(lane>>5)
#pragma unroll
    for (int mt = 0; mt < 2; mt++)
#pragma unroll
        for (int nt = 0; nt < 2; nt++) {
            const int colg = tn * TN + wn * 64 + nt * 32 + lm;
#pragma unroll
            for (int rg = 0; rg < 4; rg++) {
                const int rowg = tm * TM + wm * 64 + mt * 32 + rg * 8 + 4 * lk;
                if (MODE == 2) {
                    bf16_t* p = (bf16_t*)Cv + (size_t)batch * strideC
                                  + (size_t)rowg * Ncols + colg;
#pragma unroll
                    for (int j = 0; j < 4; j++)
                        p[(size_t)j * Ncols] = (bf16_t)(acc[mt][nt][rg * 4 + j] * scale);
                } else {
                    float* p = (float*)Cv + (size_t)batch * strideC
                                  + (size_t)rowg * Ncols + colg;
#pragma unroll
                    for (int j = 0; j < 4; j++)
                        p[(size_t)j * Ncols] = acc[mt][nt][rg * 4 + j];
                }
            }
        }
}

// ---- fused key/value GEMM ---------------------------------------------------
// tn < 8 : C1 = x @ Wa^T + ba   -> key [B,N,D] row-major bf16
// tn >= 8: C2 = (x @ Wo^T + bo)^T -> vT [B,D,N] (transposed write) bf16
__global__ __launch_bounds__(256)
void gemm_kv(const bf16_t* __restrict__ A,
             const bf16_t* __restrict__ Wa, const bf16_t* __restrict__ Wo,
             const float* __restrict__ ba, const float* __restrict__ bo,
             bf16_t* __restrict__ key, bf16_t* __restrict__ vT,
             int Nn, int Dd, int K)
{
    __shared__ bf16_t As[TM * BK];
    __shared__ bf16_t Bs[TN * BK];

    const int t    = threadIdx.x;
    const int w    = t >> 6;
    const int lane = t & 63;
    const int wm = w >> 1, wn = w & 1;
    const int lm = lane & 31;
    const int lk = lane >> 5;

    const int tiles_m = Nn / TM;             // 16
    const int per_batch = tiles_m * 16;      // 16 n-tiles (8 key + 8 value)
    const int batch = blockIdx.x / per_batch;
    const int rest  = blockIdx.x % per_batch;
    const int tm    = rest % tiles_m;
    const int tn    = rest / tiles_m;
    const bool isK  = (tn < 8);

    const bf16_t* Ab = A + (size_t)batch * Nn * K + (size_t)tm * TM * K;
    const bf16_t* Bb = (isK ? Wa + (size_t)tn * TN * K
                            : Wo + (size_t)(tn - 8) * TN * K);
    const float* bias = isK ? ba : bo;

    f32x16 acc[2][2];
#pragma unroll
    for (int i = 0; i < 2; i++)
#pragma unroll
        for (int j = 0; j < 2; j++)
#pragma unroll
            for (int e = 0; e < 16; e++) acc[i][j][e] = 0.f;

    for (int k0 = 0; k0 < K; k0 += BK) {
        stage_tiles(Ab, Bb, As, Bs, k0, K, t, w);
        __syncthreads();

        bf16x8 af[2][2], bf[2][2];
#pragma unroll
        for (int ks = 0; ks < 2; ks++) {
#pragma unroll
            for (int mt = 0; mt < 2; mt++)
                af[ks][mt] = *(const bf16x8*)&As[frag_idx(wm * 64 + mt * 32 + lm, ks * 2 + lk)];
#pragma unroll
            for (int nt = 0; nt < 2; nt++)
                bf[ks][nt] = *(const bf16x8*)&Bs[frag_idx(wn * 64 + nt * 32 + lm, ks * 2 + lk)];
        }
#pragma unroll
        for (int ks = 0; ks < 2; ks++)
#pragma unroll
            for (int mt = 0; mt < 2; mt++)
#pragma unroll
                for (int nt = 0; nt < 2; nt++)
                    acc[mt][nt] = __builtin_amdgcn_mfma_f32_32x32x16_bf16(
                        af[ks][mt], bf[ks][nt], acc[mt][nt], 0, 0, 0);
        __syncthreads();
    }

#pragma unroll
    for (int mt = 0; mt < 2; mt++)
#pragma unroll
        for (int nt = 0; nt < 2; nt++) {
            const int cw = (tn & 7) * TN + wn * 64 + nt * 32 + lm;  // col in [0,1024)
            const float bv = bias[cw];
#pragma unroll
            for (int rg = 0; rg < 4; rg++) {
                const int rowg = tm * TM + wm * 64 + mt * 32 + rg * 8 + 4 * lk;
                if (isK) {
                    bf16_t* p = key + (size_t)batch * Nn * Dd + (size_t)rowg * Dd + cw;
#pragma unroll
                    for (int j = 0; j < 4; j++)
                        p[(size_t)j * Dd] = (bf16_t)(acc[mt][nt][rg * 4 + j] + bv);
                } else {
                    // transposed: 4 regs are 4 consecutive rows -> 8B packed store
                    bf16_t* p = vT + (size_t)batch * Dd * Nn + (size_t)cw * Nn + rowg;
                    bf16x4 pk;
#pragma unroll
                    for (int j = 0; j < 4; j++)
                        pk[j] = (bf16_t)(acc[mt][nt][rg * 4 + j] + bv);
                    *(bf16x4*)p = pk;
                }
            }
        }
}

// In-place row softmax over rows of length 2048 (bf16), one block per row.
__global__ __launch_bounds__(256)
void softmax_rows(bf16_t* __restrict__ S)
{
    __shared__ float red[8];
    const int t = threadIdx.x;
    const int w = t >> 6;
    const int lane = t & 63;
    bf16_t* p = S + (size_t)blockIdx.x * 2048;

    bf16x8 v = *(const bf16x8*)&p[t * 8];
    float x[8];
    float m = -1e30f;
#pragma unroll
    for (int i = 0; i < 8; i++) { x[i] = (float)v[i]; m = fmaxf(m, x[i]); }
#pragma unroll
    for (int off = 32; off >= 1; off >>= 1) m = fmaxf(m, __shfl_xor(m, off));
    if (lane == 0) red[w] = m;
    __syncthreads();
    m = fmaxf(fmaxf(red[0], red[1]), fmaxf(red[2], red[3]));

    float s = 0.f;
#pragma unroll
    for (int i = 0; i < 8; i++) { x[i] = __expf(x[i] - m); s += x[i]; }
#pragma unroll
    for (int off = 32; off >= 1; off >>= 1) s += __shfl_xor(s, off);
    if (lane == 0) red[4 + w] = s;
    __syncthreads();
    const float inv = 1.f / (red[4] + red[5] + red[6] + red[7]);

    bf16x8 o;
#pragma unroll
    for (int i = 0; i < 8; i++) o[i] = (bf16_t)(x[i] * inv);
    *(bf16x8*)&p[t * 8] = o;
}

extern "C" void kernel_launch(void* const* d_in, const int* in_sizes, int n_in,
                              void* d_out, int out_size, void* d_ws, size_t ws_size,
                              hipStream_t stream)
{
    const int Bn = 8, Nn = 2048, Dd = 1024;

    const float* x  = (const float*)d_in[0];
    const float* Wa = (const float*)d_in[1];
    const float* ba = (const float*)d_in[2];
    const float* Wo = (const float*)d_in[3];
    const float* bo = (const float*)d_in[4];
    float* out = (float*)d_out;

    const size_t nX = (size_t)Bn * Nn * Dd;
    const size_t nW = (size_t)Dd * Dd;
    const size_t nS = (size_t)Bn * Nn * Nn;

    bf16_t* xb  = (bf16_t*)d_ws;          // [B, N, D] bf16
    bf16_t* Wab = xb + nX;                // [D, D]
    bf16_t* Wob = Wab + nW;               // [D, D]
    bf16_t* key = Wob + nW;               // [B, N, D]
    bf16_t* vT  = key + nX;               // [B, D, N]
    bf16_t* S   = vT + nX;                // [B, N, N]
    const size_t needed = (nX * 3 + nW * 2 + nS) * sizeof(bf16_t);
    if (ws_size < needed)
        fprintf(stderr, "kernel_launch: ws too small: have %zu need %zu\n", ws_size, needed);

    const dim3 blk(256);
    const long long sXN = (long long)Nn * Dd;
    const long long sS  = (long long)Nn * Nn;
    const long long sVT = (long long)Dd * Nn;

    cvt_f32_bf16<<<dim3(16384), blk, 0, stream>>>(x, xb, (int)nX);
    cvt_f32_bf16<<<dim3(1024), blk, 0, stream>>>(Wa, Wab, (int)nW);
    cvt_f32_bf16<<<dim3(1024), blk, 0, stream>>>(Wo, Wob, (int)nW);

    // key = x@Wa^T+ba ; vT = (x@Wo^T+bo)^T   (one fused dispatch)
    gemm_kv<<<dim3(Bn * 16 * 16), blk, 0, stream>>>(
        xb, Wab, Wob, ba, bo, key, vT, Nn, Dd, Dd);

    // S = (x @ key^T) / 32   [B,N,N] bf16
    gemm_nt<2><<<dim3(Bn * 16 * 16), blk, 0, stream>>>(
        xb, key, S, 0.03125f, Nn, Dd, sXN, sXN, sS, 16, 16);

    // P = softmax(S) in place
    softmax_rows<<<dim3(Bn * Nn), blk, 0, stream>>>(S);

    // out = P @ (vT)^T   [B,N,D] f32
    gemm_nt<3><<<dim3(Bn * 16 * 8), blk, 0, stream>>>(
        S, vT, (void*)out, 1.0f, Dd, Nn, sS, sVT, sXN, 16, 8);
}